// Round 11
// baseline (371.379 us; speedup 1.0000x reference)
//
#include <hip/hip_runtime.h>
#include <hip/hip_bf16.h>

#define NN 50000
#define NE 400000
#define NPAIR 12500        // NE/32: one 32-edge pair per wave
#define NCH 196            // ceil(50176/256) scan chunks
#define NPAD 50176         // NCH*256

typedef __bf16 bf16_t;
typedef __bf16 bf16x4 __attribute__((ext_vector_type(4)));
typedef __bf16 bf16x8 __attribute__((ext_vector_type(8)));
typedef float  floatx4 __attribute__((ext_vector_type(4)));

static __device__ __forceinline__ floatx4 mfma16(bf16x8 a, bf16x8 b, floatx4 c) {
    return __builtin_amdgcn_mfma_f32_16x16x32_bf16(a, b, c, 0, 0, 0);
}
static __device__ __forceinline__ float sigm_f(float x) {
    return 1.f / (1.f + __expf(-x));
}
static __device__ __forceinline__ float tanh_f(float x) {
    return 1.f - 2.f / (__expf(2.f * x) + 1.f);
}
static __device__ __forceinline__ bf16x8 cvt8(const float* sp) {
    float4 f0 = *(const float4*)sp;
    float4 f1 = *(const float4*)(sp + 4);
    bf16x8 v;
    v[0] = (bf16_t)f0.x; v[1] = (bf16_t)f0.y; v[2] = (bf16_t)f0.z; v[3] = (bf16_t)f0.w;
    v[4] = (bf16_t)f1.x; v[5] = (bf16_t)f1.y; v[6] = (bf16_t)f1.z; v[7] = (bf16_t)f1.w;
    return v;
}

// ---------------------------------------------------------------------------
// prep (fused): bf16 h copy + weight transforms into MFMA-fragment-linear.
// ---------------------------------------------------------------------------
__global__ __launch_bounds__(256) void prep_kernel(
    const float* __restrict__ nf,
    const float* __restrict__ Wm1, const float* __restrict__ Wm2,
    const float* __restrict__ Wx,  const float* __restrict__ Wh,
    const float* __restrict__ Wr1,
    bf16_t* __restrict__ hb,
    bf16_t* __restrict__ W1f, bf16_t* __restrict__ W2f,
    bf16_t* __restrict__ Wxt, bf16_t* __restrict__ Wht,
    bf16_t* __restrict__ Wr1f)
{
    int u = blockIdx.x * 256 + threadIdx.x;
    if (u < 800000) {          // hb: 4 elems per thread
        float4 v = *(const float4*)(nf + (size_t)u * 4);
        bf16x4 o;
        o[0] = (bf16_t)v.x; o[1] = (bf16_t)v.y; o[2] = (bf16_t)v.z; o[3] = (bf16_t)v.w;
        *(bf16x4*)(hb + (size_t)u * 4) = o;
        return;
    }
    u -= 800000;
    if (u < 20480) {
        int j = u & 7, l = (u >> 3) & 63, rem = u >> 9;   // rem 0..39
        int ks = rem % 5, nt = rem / 5;
        int n = nt * 16 + (l & 15);
        int k = ks * 32 + (l >> 4) * 8 + j;
        W1f[u] = (k < 136) ? (bf16_t)Wm1[k * 128 + n] : (bf16_t)0.f;
        return;
    }
    u -= 20480;
    if (u < 8192) {
        int j = u & 7, l = (u >> 3) & 63, rem = u >> 9;   // rem 0..15
        int kg = rem & 3, nt = rem >> 2;
        int n = nt * 16 + (l & 15);
        int k = kg * 32 + (l >> 4) * 8 + j;
        W2f[u] = (bf16_t)Wm2[k * 64 + n];
        return;
    }
    u -= 8192;
    if (u < 12288) {
        int n = u >> 6, k = u & 63;
        Wxt[u] = (bf16_t)Wx[k * 192 + n];
        return;
    }
    u -= 12288;
    if (u < 12288) {
        int n = u >> 6, k = u & 63;
        Wht[u] = (bf16_t)Wh[k * 192 + n];
        return;
    }
    u -= 12288;
    if (u < 8192) {            // Wr1f
        int j = u & 7, l = (u >> 3) & 63, rem = u >> 9;   // rem 0..15
        int kg = rem & 1, nt = rem >> 1;
        int n = nt * 16 + (l & 15);
        int k = kg * 32 + (l >> 4) * 8 + j;
        Wr1f[u] = (bf16_t)Wr1[k * 128 + n];
    }
}

// ---------------------------------------------------------------------------
// CSR build: hist -> scan -> scatter (permute srcs/dsts/ef->bf16, dst-sorted)
// ---------------------------------------------------------------------------
__global__ __launch_bounds__(256) void hist_kernel(
    const int* __restrict__ edst, int* __restrict__ deg)
{
    int e = blockIdx.x * 256 + threadIdx.x;
    if (e < NE) atomicAdd(&deg[edst[e]], 1);
}

__global__ __launch_bounds__(256) void scanA_kernel(
    const int* __restrict__ deg, int* __restrict__ chunkSums)
{
    __shared__ int s[256];
    int i = blockIdx.x * 256 + threadIdx.x;
    s[threadIdx.x] = deg[i];
    __syncthreads();
    for (int st = 128; st >= 1; st >>= 1) {
        if (threadIdx.x < st) s[threadIdx.x] += s[threadIdx.x + st];
        __syncthreads();
    }
    if (threadIdx.x == 0) chunkSums[blockIdx.x] = s[0];
}

__global__ __launch_bounds__(256) void scanB_kernel(
    const int* __restrict__ chunkSums, int* __restrict__ chunkOff)
{
    __shared__ int s[256];
    int t = threadIdx.x;
    int v = (t < NCH) ? chunkSums[t] : 0;
    s[t] = v;
    __syncthreads();
    for (int st = 1; st < 256; st <<= 1) {
        int add = (t >= st) ? s[t - st] : 0;
        __syncthreads();
        s[t] += add;
        __syncthreads();
    }
    if (t < NCH) chunkOff[t] = s[t] - v;   // exclusive
}

__global__ __launch_bounds__(256) void scanC_kernel(
    const int* __restrict__ deg, const int* __restrict__ chunkOff,
    int* __restrict__ cursor)
{
    __shared__ int s[256];
    int t = threadIdx.x;
    int i = blockIdx.x * 256 + t;
    int v = deg[i];
    s[t] = v;
    __syncthreads();
    for (int st = 1; st < 256; st <<= 1) {
        int add = (t >= st) ? s[t - st] : 0;
        __syncthreads();
        s[t] += add;
        __syncthreads();
    }
    cursor[i] = chunkOff[blockIdx.x] + s[t] - v;   // exclusive
}

__global__ __launch_bounds__(256) void scatter_kernel(
    const int* __restrict__ esrc, const int* __restrict__ edst,
    const float* __restrict__ ef,
    int* __restrict__ cursor, int* __restrict__ srcs, int* __restrict__ dsts,
    bf16_t* __restrict__ efpb)
{
    int e = blockIdx.x * 256 + threadIdx.x;
    if (e >= NE) return;
    int d = edst[e];
    int p = atomicAdd(&cursor[d], 1);
    srcs[p] = esrc[e];
    dsts[p] = d;
    float4 a = *(const float4*)(ef + (size_t)e * 8);
    float4 b = *(const float4*)(ef + (size_t)e * 8 + 4);
    bf16x8 v;
    v[0] = (bf16_t)a.x; v[1] = (bf16_t)a.y; v[2] = (bf16_t)a.z; v[3] = (bf16_t)a.w;
    v[4] = (bf16_t)b.x; v[5] = (bf16_t)b.y; v[6] = (bf16_t)b.z; v[7] = (bf16_t)b.w;
    *(bf16x8*)(efpb + (size_t)p * 8) = v;
}

// ---------------------------------------------------------------------------
// edge kernel v11: THROUGHPUT launch — 3125 non-persistent blocks, exactly
// one 32-edge pair per wave (12500 waves, ~12 generations/CU). R8/R9/R10 all
// ran 69-72us with grid==residency (2-4k total waves, measured ~6 waves/CU):
// the persistent design starves wave supply and exposes every latency. W1 in
// LDS (shared per block), W2 in per-wave registers (16 coalesced L2 loads;
// LDS 50.2KB -> 3 blocks/CU). Default bounds (R7: caps spill arrays).
// ---------------------------------------------------------------------------
__global__ __launch_bounds__(256) void edge_kernel(
    const bf16_t* __restrict__ hb, const bf16_t* __restrict__ efpb,
    const int* __restrict__ srcs, const int* __restrict__ dsts,
    const bf16_t* __restrict__ W1f, const bf16_t* __restrict__ W2f,
    const float* __restrict__ b1f, const float* __restrict__ b2f,
    float* __restrict__ agg)
{
    __shared__ __attribute__((aligned(16))) bf16_t w1s[20480];      // 40960 B
    __shared__ __attribute__((aligned(16))) bf16_t hq[4][32 * 36];  //  9216 B

    const int tid = threadIdx.x;
    {
        const uint4* s1 = (const uint4*)W1f;
        uint4* d1 = (uint4*)w1s;
        #pragma unroll
        for (int i = 0; i < 10; i++) d1[tid + i * 256] = s1[tid + i * 256];
    }

    const int lane = tid & 63;
    const int wv   = tid >> 6;
    const int l15  = lane & 15;
    const int quad = lane >> 4;

    // W2 fragments in registers (frag-linear, coalesced, L2-hot)
    bf16x8 w2f[4][4];
    #pragma unroll
    for (int nt = 0; nt < 4; nt++)
        #pragma unroll
        for (int kg = 0; kg < 4; kg++)
            w2f[nt][kg] = *(const bf16x8*)(W2f + ((nt * 4 + kg) * 64 + lane) * 8);

    float b1r[8], b2r[4];
    #pragma unroll
    for (int nt = 0; nt < 8; nt++) b1r[nt] = b1f[nt * 16 + l15];
    #pragma unroll
    for (int nt = 0; nt < 4; nt++) b2r[nt] = b2f[nt * 16 + l15];

    // this wave's 32 sorted edges
    const int p = blockIdx.x * 4 + wv;       // p < NPAIR (grid*4 == NPAIR)
    const int base = p * 32;
    const int r0 = base + l15, r1 = base + 16 + l15;

    bf16x8 af0[5], af1[5];
    int4 d40, d41;
    {
        int si0 = srcs[r0], di0 = dsts[r0];
        int si1 = srcs[r1], di1 = dsts[r1];
        const bf16_t* sp0 = hb + (size_t)si0 * 64 + quad * 8;
        const bf16_t* dp0 = hb + (size_t)di0 * 64 + quad * 8;
        const bf16_t* sp1 = hb + (size_t)si1 * 64 + quad * 8;
        const bf16_t* dp1 = hb + (size_t)di1 * 64 + quad * 8;
        af0[0] = *(const bf16x8*)sp0;  af0[1] = *(const bf16x8*)(sp0 + 32);
        af0[2] = *(const bf16x8*)dp0;  af0[3] = *(const bf16x8*)(dp0 + 32);
        af1[0] = *(const bf16x8*)sp1;  af1[1] = *(const bf16x8*)(sp1 + 32);
        af1[2] = *(const bf16x8*)dp1;  af1[3] = *(const bf16x8*)(dp1 + 32);
        if (quad == 0) {
            af0[4] = *(const bf16x8*)(efpb + (size_t)r0 * 8);
            af1[4] = *(const bf16x8*)(efpb + (size_t)r1 * 8);
        } else {
            #pragma unroll
            for (int q = 0; q < 8; q++) { af0[4][q] = (bf16_t)0.f; af1[4][q] = (bf16_t)0.f; }
        }
        d40 = *(const int4*)(dsts + base + quad * 4);
        d41 = *(const int4*)(dsts + base + 16 + quad * 4);
    }
    __syncthreads();   // W1 staging visible

    floatx4 oa0[4], oa1[4];
    #pragma unroll
    for (int nt = 0; nt < 4; nt++) {
        oa0[nt].x=0.f; oa0[nt].y=0.f; oa0[nt].z=0.f; oa0[nt].w=0.f;
        oa1[nt].x=0.f; oa1[nt].y=0.f; oa1[nt].z=0.f; oa1[nt].w=0.f;
    }

    #pragma unroll
    for (int q = 0; q < 4; q++) {
        floatx4 ac0[2], ac1[2];
        #pragma unroll
        for (int nt = 0; nt < 2; nt++) {
            ac0[nt].x=0.f; ac0[nt].y=0.f; ac0[nt].z=0.f; ac0[nt].w=0.f;
            ac1[nt].x=0.f; ac1[nt].y=0.f; ac1[nt].z=0.f; ac1[nt].w=0.f;
        }
        #pragma unroll
        for (int nt = 0; nt < 2; nt++) {
            int gnt = q * 2 + nt;
            #pragma unroll
            for (int ks = 0; ks < 5; ks++) {
                bf16x8 b = *(const bf16x8*)(w1s + ((gnt * 5 + ks) * 64 + lane) * 8);
                ac0[nt] = mfma16(af0[ks], b, ac0[nt]);
                ac1[nt] = mfma16(af1[ks], b, ac1[nt]);
            }
        }
        #pragma unroll
        for (int nt = 0; nt < 2; nt++) {
            float bb = b1r[q * 2 + nt];
            #pragma unroll
            for (int r = 0; r < 4; r++) {
                float v0 = fmaxf(ac0[nt][r] + bb, 0.f);
                float v1 = fmaxf(ac1[nt][r] + bb, 0.f);
                hq[wv][(quad * 4 + r) * 36 + nt * 16 + l15]      = (bf16_t)v0;
                hq[wv][(16 + quad * 4 + r) * 36 + nt * 16 + l15] = (bf16_t)v1;
            }
        }
        // same-wave write->read (compiler lgkmcnt)
        bf16x8 hf0 = *(const bf16x8*)(hq[wv] + l15 * 36 + quad * 8);
        bf16x8 hf1 = *(const bf16x8*)(hq[wv] + (16 + l15) * 36 + quad * 8);
        #pragma unroll
        for (int nt = 0; nt < 4; nt++) {
            oa0[nt] = mfma16(hf0, w2f[nt][q], oa0[nt]);
            oa1[nt] = mfma16(hf1, w2f[nt][q], oa1[nt]);
        }
    }

    // epilogue: merged atomics over sorted dsts, both groups
    #pragma unroll
    for (int nt = 0; nt < 4; nt++) {
        int col = nt * 16 + l15;
        float bb = b2r[nt];
        float* ap = agg + col;
        {
            int dcur = d40.x;
            float v = oa0[nt][0] + bb;
            if (d40.y == dcur) v += oa0[nt][1] + bb;
            else { atomicAdd(ap + (size_t)dcur * 64, v); dcur = d40.y; v = oa0[nt][1] + bb; }
            if (d40.z == dcur) v += oa0[nt][2] + bb;
            else { atomicAdd(ap + (size_t)dcur * 64, v); dcur = d40.z; v = oa0[nt][2] + bb; }
            if (d40.w == dcur) v += oa0[nt][3] + bb;
            else { atomicAdd(ap + (size_t)dcur * 64, v); dcur = d40.w; v = oa0[nt][3] + bb; }
            atomicAdd(ap + (size_t)dcur * 64, v);
        }
        {
            int dcur = d41.x;
            float v = oa1[nt][0] + bb;
            if (d41.y == dcur) v += oa1[nt][1] + bb;
            else { atomicAdd(ap + (size_t)dcur * 64, v); dcur = d41.y; v = oa1[nt][1] + bb; }
            if (d41.z == dcur) v += oa1[nt][2] + bb;
            else { atomicAdd(ap + (size_t)dcur * 64, v); dcur = d41.z; v = oa1[nt][2] + bb; }
            if (d41.w == dcur) v += oa1[nt][3] + bb;
            else { atomicAdd(ap + (size_t)dcur * 64, v); dcur = d41.w; v = oa1[nt][3] + bb; }
            atomicAdd(ap + (size_t)dcur * 64, v);
        }
    }
}

// ---------------------------------------------------------------------------
// GRU (MFMA): 64 nodes/block, 16/wave. LAST=0: emits fp32 h + bf16 hb and
// zeroes agg in place (replaces step-1 memset). LAST=1: fused readout MLP.
// ---------------------------------------------------------------------------
template<int LAST>
__global__ __launch_bounds__(256) void gru_kernel(
    float* __restrict__ agg, const float* __restrict__ h_in,
    float* __restrict__ h_out, bf16_t* __restrict__ hb_out,
    const bf16_t* __restrict__ Wxt, const bf16_t* __restrict__ Wht,
    const float* __restrict__ bg,
    const bf16_t* __restrict__ Wr1f, const float* __restrict__ br1,
    const float* __restrict__ Wr2, const float* __restrict__ br2,
    float* __restrict__ out)
{
    __shared__ __attribute__((aligned(16))) float  shd[64 * 68];    // 17408 B
    __shared__ __attribute__((aligned(16))) bf16_t hb2[4][16 * 72]; //  9216 B
    const int tid = threadIdx.x;
    const int n0  = blockIdx.x * 64;

    for (int idx = tid; idx < 64 * 16; idx += 256) {
        int i = idx >> 4, c = (idx & 15) * 4;
        int n = n0 + i; if (n >= NN) n = NN - 1;
        *(float4*)&shd[i * 68 + c] = *(const float4*)(h_in + (size_t)n * 64 + c);
    }
    __syncthreads();

    const int lane = tid & 63;
    const int wv   = tid >> 6;
    const int l15  = lane & 15;
    const int quad = lane >> 4;
    const int rowA = wv * 16 + l15;
    const bool rowOK = (n0 + rowA) < NN;
    int nA = n0 + rowA; if (!rowOK) nA = NN - 1;

    bf16x8 ax[2], ah[2];
    ax[0] = cvt8(agg + (size_t)nA * 64 + quad * 8);
    ax[1] = cvt8(agg + (size_t)nA * 64 + quad * 8 + 32);
    {
        const float* hp = shd + rowA * 68 + quad * 8;
        ah[0] = cvt8(hp);
        ah[1] = cvt8(hp + 32);
    }
    if (!LAST && rowOK) {
        float4 z = make_float4(0.f, 0.f, 0.f, 0.f);
        *(float4*)(agg + (size_t)nA * 64 + quad * 8)      = z;
        *(float4*)(agg + (size_t)nA * 64 + quad * 8 + 4)  = z;
        *(float4*)(agg + (size_t)nA * 64 + quad * 8 + 32) = z;
        *(float4*)(agg + (size_t)nA * 64 + quad * 8 + 36) = z;
    }

    floatx4 az[4], ar[4], axh[4], ahh[4];
    #pragma unroll
    for (int nt = 0; nt < 4; nt++) {
        az[nt].x=0.f; az[nt].y=0.f; az[nt].z=0.f; az[nt].w=0.f;
        ar[nt].x=0.f; ar[nt].y=0.f; ar[nt].z=0.f; ar[nt].w=0.f;
        axh[nt].x=0.f; axh[nt].y=0.f; axh[nt].z=0.f; axh[nt].w=0.f;
        ahh[nt].x=0.f; ahh[nt].y=0.f; ahh[nt].z=0.f; ahh[nt].w=0.f;
    }
    #pragma unroll
    for (int nt = 0; nt < 4; nt++) {
        const bf16_t* bx_z = Wxt + (nt * 16 + l15) * 64 + quad * 8;
        const bf16_t* bh_z = Wht + (nt * 16 + l15) * 64 + quad * 8;
        const bf16_t* bx_r = bx_z + 64 * 64;
        const bf16_t* bh_r = bh_z + 64 * 64;
        const bf16_t* bx_h = bx_z + 128 * 64;
        const bf16_t* bh_h = bh_z + 128 * 64;
        az[nt]  = mfma16(ax[0], *(const bf16x8*)bx_z,        az[nt]);
        az[nt]  = mfma16(ax[1], *(const bf16x8*)(bx_z + 32), az[nt]);
        az[nt]  = mfma16(ah[0], *(const bf16x8*)bh_z,        az[nt]);
        az[nt]  = mfma16(ah[1], *(const bf16x8*)(bh_z + 32), az[nt]);
        ar[nt]  = mfma16(ax[0], *(const bf16x8*)bx_r,        ar[nt]);
        ar[nt]  = mfma16(ax[1], *(const bf16x8*)(bx_r + 32), ar[nt]);
        ar[nt]  = mfma16(ah[0], *(const bf16x8*)bh_r,        ar[nt]);
        ar[nt]  = mfma16(ah[1], *(const bf16x8*)(bh_r + 32), ar[nt]);
        axh[nt] = mfma16(ax[0], *(const bf16x8*)bx_h,        axh[nt]);
        axh[nt] = mfma16(ax[1], *(const bf16x8*)(bx_h + 32), axh[nt]);
        ahh[nt] = mfma16(ah[0], *(const bf16x8*)bh_h,        ahh[nt]);
        ahh[nt] = mfma16(ah[1], *(const bf16x8*)(bh_h + 32), ahh[nt]);
    }

    #pragma unroll
    for (int nt = 0; nt < 4; nt++) {
        int j = nt * 16 + l15;
        float bz = bg[j], brr = bg[64 + j], bh = bg[128 + j];
        #pragma unroll
        for (int r = 0; r < 4; r++) {
            int lrow = wv * 16 + quad * 4 + r;
            int n = n0 + lrow;
            float z  = sigm_f(az[nt][r] + bz);
            float rr = sigm_f(ar[nt][r] + brr);
            float hc = tanh_f(axh[nt][r] + bh + rr * ahh[nt][r]);
            float hold = shd[lrow * 68 + j];
            float hnew = z * hold + (1.f - z) * hc;
            if (LAST) {
                hb2[wv][(quad * 4 + r) * 72 + j] = (bf16_t)hnew;
            } else if (n < NN) {
                h_out[(size_t)n * 64 + j]  = hnew;
                hb_out[(size_t)n * 64 + j] = (bf16_t)hnew;
            }
        }
    }

    if (LAST) {
        bf16x8 a0 = *(const bf16x8*)(hb2[wv] + l15 * 72 + quad * 8);
        bf16x8 a1 = *(const bf16x8*)(hb2[wv] + l15 * 72 + quad * 8 + 32);
        floatx4 accR[8];
        #pragma unroll
        for (int nt = 0; nt < 8; nt++) { accR[nt].x=0.f; accR[nt].y=0.f; accR[nt].z=0.f; accR[nt].w=0.f; }
        #pragma unroll
        for (int nt = 0; nt < 8; nt++) {
            bf16x8 b0 = *(const bf16x8*)(Wr1f + ((nt * 2 + 0) * 64 + lane) * 8);
            bf16x8 b1 = *(const bf16x8*)(Wr1f + ((nt * 2 + 1) * 64 + lane) * 8);
            accR[nt] = mfma16(a0, b0, accR[nt]);
            accR[nt] = mfma16(a1, b1, accR[nt]);
        }
        float br1r[8], wr2r[8];
        #pragma unroll
        for (int nt = 0; nt < 8; nt++) {
            br1r[nt] = br1[nt * 16 + l15];
            wr2r[nt] = Wr2[nt * 16 + l15];
        }
        float br2v = br2[0];
        #pragma unroll
        for (int r = 0; r < 4; r++) {
            float p = 0.f;
            #pragma unroll
            for (int nt = 0; nt < 8; nt++)
                p += fmaxf(accR[nt][r] + br1r[nt], 0.f) * wr2r[nt];
            p += __shfl_xor(p, 1, 64);
            p += __shfl_xor(p, 2, 64);
            p += __shfl_xor(p, 4, 64);
            p += __shfl_xor(p, 8, 64);
            if (l15 == 0) {
                int n = n0 + wv * 16 + quad * 4 + r;
                if (n < NN) out[n] = p + br2v;
            }
        }
    }
}

// ---------------------------------------------------------------------------
extern "C" void kernel_launch(void* const* d_in, const int* in_sizes, int n_in,
                              void* d_out, int out_size, void* d_ws, size_t ws_size,
                              hipStream_t stream)
{
    const float* nf  = (const float*)d_in[0];
    const float* ef  = (const float*)d_in[1];
    const int* esrc  = (const int*)d_in[2];
    const int* edst  = (const int*)d_in[3];
    const float* Wm1 = (const float*)d_in[4];
    const float* bm1 = (const float*)d_in[5];
    const float* Wm2 = (const float*)d_in[6];
    const float* bm2 = (const float*)d_in[7];
    const float* Wx  = (const float*)d_in[8];
    const float* Wh  = (const float*)d_in[9];
    const float* bg  = (const float*)d_in[10];
    const float* Wr1 = (const float*)d_in[11];
    const float* br1 = (const float*)d_in[12];
    const float* Wr2 = (const float*)d_in[13];
    const float* br2 = (const float*)d_in[14];

    char* ws = (char*)d_ws;
    float*  hbuf   = (float*)(ws);                   // 12,800,000
    bf16_t* hb     = (bf16_t*)(ws + 12800000);       // 6,400,000
    bf16_t* W1f    = (bf16_t*)(ws + 19200000);       // 40,960
    bf16_t* W2f    = (bf16_t*)(ws + 19240960);       // 16,384
    bf16_t* Wxt    = (bf16_t*)(ws + 19257344);       // 24,576
    bf16_t* Wht    = (bf16_t*)(ws + 19281920);       // 24,576
    bf16_t* Wr1f   = (bf16_t*)(ws + 19306496);       // 16,384
    int*    srcs   = (int*)(ws + 19322880);          // 1,600,000
    int*    dsts   = (int*)(ws + 20922880);          // 1,600,000
    bf16_t* efpb   = (bf16_t*)(ws + 22522880);       // 6,400,000
    int*    deg    = (int*)(ws + 28922880);          // 200,704
    float*  agg    = (float*)(ws + 29123584);        // 12,800,000 (adjacent to deg)
    int*    cursor = (int*)(ws + 41923584);          // 200,704
    int*    chunkS = (int*)(ws + 42124288);          // 1,024
    int*    chunkO = (int*)(ws + 42125312);          // 1,024

    prep_kernel<<<3365, 256, 0, stream>>>(nf, Wm1, Wm2, Wx, Wh, Wr1,
                                          hb, W1f, W2f, Wxt, Wht, Wr1f);

    // one memset covers deg + agg (adjacent)
    hipMemsetAsync(deg, 0, (size_t)NPAD * 4 + (size_t)NN * 64 * 4, stream);
    hist_kernel<<<(NE + 255) / 256, 256, 0, stream>>>(edst, deg);
    scanA_kernel<<<NCH, 256, 0, stream>>>(deg, chunkS);
    scanB_kernel<<<1, 256, 0, stream>>>(chunkS, chunkO);
    scanC_kernel<<<NCH, 256, 0, stream>>>(deg, chunkO, cursor);
    scatter_kernel<<<(NE + 255) / 256, 256, 0, stream>>>(esrc, edst, ef, cursor,
                                                         srcs, dsts, efpb);

    // step 0
    edge_kernel<<<NPAIR / 4, 256, 0, stream>>>(hb, efpb, srcs, dsts,
                                               W1f, W2f, bm1, bm2, agg);
    gru_kernel<0><<<(NN + 63) / 64, 256, 0, stream>>>(
        agg, nf, hbuf, hb, Wxt, Wht, bg, Wr1f, br1, Wr2, br2, (float*)d_out);
    // step 1 (agg zeroed by gru<0>)
    edge_kernel<<<NPAIR / 4, 256, 0, stream>>>(hb, efpb, srcs, dsts,
                                               W1f, W2f, bm1, bm2, agg);
    gru_kernel<1><<<(NN + 63) / 64, 256, 0, stream>>>(
        agg, hbuf, nullptr, nullptr, Wxt, Wht, bg, Wr1f, br1, Wr2, br2,
        (float*)d_out);
}

// Round 12
// 322.839 us; speedup vs baseline: 1.1504x; 1.1504x over previous
//
#include <hip/hip_runtime.h>
#include <hip/hip_bf16.h>

#define NN 50000
#define NE 400000
#define NPAIR 12500        // NE/32: 32 sorted edges per wave-iteration
#define NCH 196            // ceil(50176/256) scan chunks
#define NPAD 50176         // NCH*256

typedef __bf16 bf16_t;
typedef __bf16 bf16x4 __attribute__((ext_vector_type(4)));
typedef __bf16 bf16x8 __attribute__((ext_vector_type(8)));
typedef float  floatx4 __attribute__((ext_vector_type(4)));

static __device__ __forceinline__ floatx4 mfma16(bf16x8 a, bf16x8 b, floatx4 c) {
    return __builtin_amdgcn_mfma_f32_16x16x32_bf16(a, b, c, 0, 0, 0);
}
static __device__ __forceinline__ float sigm_f(float x) {
    return 1.f / (1.f + __expf(-x));
}
static __device__ __forceinline__ float tanh_f(float x) {
    return 1.f - 2.f / (__expf(2.f * x) + 1.f);
}
static __device__ __forceinline__ bf16x8 cvt8(const float* sp) {
    float4 f0 = *(const float4*)sp;
    float4 f1 = *(const float4*)(sp + 4);
    bf16x8 v;
    v[0] = (bf16_t)f0.x; v[1] = (bf16_t)f0.y; v[2] = (bf16_t)f0.z; v[3] = (bf16_t)f0.w;
    v[4] = (bf16_t)f1.x; v[5] = (bf16_t)f1.y; v[6] = (bf16_t)f1.z; v[7] = (bf16_t)f1.w;
    return v;
}

// ---------------------------------------------------------------------------
// prep (fused): bf16 h copy + weight transforms into MFMA-fragment-linear.
// ---------------------------------------------------------------------------
__global__ __launch_bounds__(256) void prep_kernel(
    const float* __restrict__ nf,
    const float* __restrict__ Wm1, const float* __restrict__ Wm2,
    const float* __restrict__ Wx,  const float* __restrict__ Wh,
    const float* __restrict__ Wr1,
    bf16_t* __restrict__ hb,
    bf16_t* __restrict__ W1f, bf16_t* __restrict__ W2f,
    bf16_t* __restrict__ Wxt, bf16_t* __restrict__ Wht,
    bf16_t* __restrict__ Wr1f)
{
    int u = blockIdx.x * 256 + threadIdx.x;
    if (u < 800000) {          // hb: 4 elems per thread
        float4 v = *(const float4*)(nf + (size_t)u * 4);
        bf16x4 o;
        o[0] = (bf16_t)v.x; o[1] = (bf16_t)v.y; o[2] = (bf16_t)v.z; o[3] = (bf16_t)v.w;
        *(bf16x4*)(hb + (size_t)u * 4) = o;
        return;
    }
    u -= 800000;
    if (u < 20480) {
        int j = u & 7, l = (u >> 3) & 63, rem = u >> 9;   // rem 0..39
        int ks = rem % 5, nt = rem / 5;
        int n = nt * 16 + (l & 15);
        int k = ks * 32 + (l >> 4) * 8 + j;
        W1f[u] = (k < 136) ? (bf16_t)Wm1[k * 128 + n] : (bf16_t)0.f;
        return;
    }
    u -= 20480;
    if (u < 8192) {
        int j = u & 7, l = (u >> 3) & 63, rem = u >> 9;   // rem 0..15
        int kg = rem & 3, nt = rem >> 2;
        int n = nt * 16 + (l & 15);
        int k = kg * 32 + (l >> 4) * 8 + j;
        W2f[u] = (bf16_t)Wm2[k * 64 + n];
        return;
    }
    u -= 8192;
    if (u < 12288) {
        int n = u >> 6, k = u & 63;
        Wxt[u] = (bf16_t)Wx[k * 192 + n];
        return;
    }
    u -= 12288;
    if (u < 12288) {
        int n = u >> 6, k = u & 63;
        Wht[u] = (bf16_t)Wh[k * 192 + n];
        return;
    }
    u -= 12288;
    if (u < 8192) {            // Wr1f
        int j = u & 7, l = (u >> 3) & 63, rem = u >> 9;   // rem 0..15
        int kg = rem & 1, nt = rem >> 1;
        int n = nt * 16 + (l & 15);
        int k = kg * 32 + (l >> 4) * 8 + j;
        Wr1f[u] = (bf16_t)Wr1[k * 128 + n];
    }
}

// ---------------------------------------------------------------------------
// CSR build: hist -> scan -> scatter (permute srcs/dsts/ef->bf16, dst-sorted)
// ---------------------------------------------------------------------------
__global__ __launch_bounds__(256) void hist_kernel(
    const int* __restrict__ edst, int* __restrict__ deg)
{
    int e = blockIdx.x * 256 + threadIdx.x;
    if (e < NE) atomicAdd(&deg[edst[e]], 1);
}

__global__ __launch_bounds__(256) void scanA_kernel(
    const int* __restrict__ deg, int* __restrict__ chunkSums)
{
    __shared__ int s[256];
    int i = blockIdx.x * 256 + threadIdx.x;
    s[threadIdx.x] = deg[i];
    __syncthreads();
    for (int st = 128; st >= 1; st >>= 1) {
        if (threadIdx.x < st) s[threadIdx.x] += s[threadIdx.x + st];
        __syncthreads();
    }
    if (threadIdx.x == 0) chunkSums[blockIdx.x] = s[0];
}

__global__ __launch_bounds__(256) void scanB_kernel(
    const int* __restrict__ chunkSums, int* __restrict__ chunkOff)
{
    __shared__ int s[256];
    int t = threadIdx.x;
    int v = (t < NCH) ? chunkSums[t] : 0;
    s[t] = v;
    __syncthreads();
    for (int st = 1; st < 256; st <<= 1) {
        int add = (t >= st) ? s[t - st] : 0;
        __syncthreads();
        s[t] += add;
        __syncthreads();
    }
    if (t < NCH) chunkOff[t] = s[t] - v;   // exclusive
}

__global__ __launch_bounds__(256) void scanC_kernel(
    const int* __restrict__ deg, const int* __restrict__ chunkOff,
    int* __restrict__ cursor)
{
    __shared__ int s[256];
    int t = threadIdx.x;
    int i = blockIdx.x * 256 + t;
    int v = deg[i];
    s[t] = v;
    __syncthreads();
    for (int st = 1; st < 256; st <<= 1) {
        int add = (t >= st) ? s[t - st] : 0;
        __syncthreads();
        s[t] += add;
        __syncthreads();
    }
    cursor[i] = chunkOff[blockIdx.x] + s[t] - v;   // exclusive
}

__global__ __launch_bounds__(256) void scatter_kernel(
    const int* __restrict__ esrc, const int* __restrict__ edst,
    const float* __restrict__ ef,
    int* __restrict__ cursor, int* __restrict__ srcs, int* __restrict__ dsts,
    bf16_t* __restrict__ efpb)
{
    int e = blockIdx.x * 256 + threadIdx.x;
    if (e >= NE) return;
    int d = edst[e];
    int p = atomicAdd(&cursor[d], 1);    // cursor ends at row-end offsets
    srcs[p] = esrc[e];
    dsts[p] = d;
    float4 a = *(const float4*)(ef + (size_t)e * 8);
    float4 b = *(const float4*)(ef + (size_t)e * 8 + 4);
    bf16x8 v;
    v[0] = (bf16_t)a.x; v[1] = (bf16_t)a.y; v[2] = (bf16_t)a.z; v[3] = (bf16_t)a.w;
    v[4] = (bf16_t)b.x; v[5] = (bf16_t)b.y; v[6] = (bf16_t)b.z; v[7] = (bf16_t)b.w;
    *(bf16x8*)(efpb + (size_t)p * 8) = v;
}

// ---------------------------------------------------------------------------
// edge kernel v12: ZERO ATOMICS. R8-R11 all plateau at 69-79us with ~11M
// device-scope atomicAdds (WRITE 43925KB/4B exactly) regardless of
// occupancy/LDS/launch shape -> rate-limited by the memory-side atomic RMW
// pipe (~0.6/cyc/channel). This version writes m[e][64] as bf16 plain
// stores in sorted-edge order; a separate agg kernel does the CSR
// gather-sum. Structure otherwise = R10 (persistent, 32 edges/wave/iter,
// W1+W2 frag-linear LDS, gather prefetched before the store epilogue).
// ---------------------------------------------------------------------------
__global__ __launch_bounds__(256) void edge_kernel(
    const bf16_t* __restrict__ hb, const bf16_t* __restrict__ efpb,
    const int* __restrict__ srcs, const int* __restrict__ dsts,
    const bf16_t* __restrict__ W1f, const bf16_t* __restrict__ W2f,
    const float* __restrict__ b1f, const float* __restrict__ b2f,
    bf16_t* __restrict__ mb)
{
    __shared__ __attribute__((aligned(16))) bf16_t w1s[20480];      // 40960 B
    __shared__ __attribute__((aligned(16))) bf16_t w2s[8192];       // 16384 B
    __shared__ __attribute__((aligned(16))) bf16_t hq[4][32 * 36];  //  9216 B

    const int tid = threadIdx.x;
    {
        const uint4* s1 = (const uint4*)W1f;
        uint4* d1 = (uint4*)w1s;
        #pragma unroll
        for (int i = 0; i < 10; i++) d1[tid + i * 256] = s1[tid + i * 256];
        const uint4* s2 = (const uint4*)W2f;
        uint4* d2 = (uint4*)w2s;
        #pragma unroll
        for (int i = 0; i < 4; i++) d2[tid + i * 256] = s2[tid + i * 256];
    }
    __syncthreads();

    const int lane = tid & 63;
    const int wv   = tid >> 6;
    const int l15  = lane & 15;
    const int quad = lane >> 4;

    float b1r[8], b2r[4];
    #pragma unroll
    for (int nt = 0; nt < 8; nt++) b1r[nt] = b1f[nt * 16 + l15];
    #pragma unroll
    for (int nt = 0; nt < 4; nt++) b2r[nt] = b2f[nt * 16 + l15];

    const int WTOT = gridDim.x * 4;
    int p = blockIdx.x * 4 + wv;           // pair index

    // gather pair-0 operands
    bf16x8 af0[5], af1[5];
    {
        int base = p * 32;
        int r0 = base + l15, r1 = base + 16 + l15;
        int si0 = srcs[r0], di0 = dsts[r0];
        int si1 = srcs[r1], di1 = dsts[r1];
        const bf16_t* sp0 = hb + (size_t)si0 * 64 + quad * 8;
        const bf16_t* dp0 = hb + (size_t)di0 * 64 + quad * 8;
        const bf16_t* sp1 = hb + (size_t)si1 * 64 + quad * 8;
        const bf16_t* dp1 = hb + (size_t)di1 * 64 + quad * 8;
        af0[0] = *(const bf16x8*)sp0;  af0[1] = *(const bf16x8*)(sp0 + 32);
        af0[2] = *(const bf16x8*)dp0;  af0[3] = *(const bf16x8*)(dp0 + 32);
        af1[0] = *(const bf16x8*)sp1;  af1[1] = *(const bf16x8*)(sp1 + 32);
        af1[2] = *(const bf16x8*)dp1;  af1[3] = *(const bf16x8*)(dp1 + 32);
        if (quad == 0) {
            af0[4] = *(const bf16x8*)(efpb + (size_t)r0 * 8);
            af1[4] = *(const bf16x8*)(efpb + (size_t)r1 * 8);
        } else {
            #pragma unroll
            for (int q = 0; q < 8; q++) { af0[4][q] = (bf16_t)0.f; af1[4][q] = (bf16_t)0.f; }
        }
    }

    while (true) {
        int pn = p + WTOT;
        int pp = (pn < NPAIR) ? pn : p;    // clamped, in-bounds
        int nbase = pp * 32;
        int nr0 = nbase + l15, nr1 = nbase + 16 + l15;
        int si0n = srcs[nr0], di0n = dsts[nr0];
        int si1n = srcs[nr1], di1n = dsts[nr1];

        floatx4 oa0[4], oa1[4];
        #pragma unroll
        for (int nt = 0; nt < 4; nt++) {
            oa0[nt].x=0.f; oa0[nt].y=0.f; oa0[nt].z=0.f; oa0[nt].w=0.f;
            oa1[nt].x=0.f; oa1[nt].y=0.f; oa1[nt].z=0.f; oa1[nt].w=0.f;
        }

        #pragma unroll
        for (int q = 0; q < 4; q++) {
            floatx4 ac0[2], ac1[2];
            #pragma unroll
            for (int nt = 0; nt < 2; nt++) {
                ac0[nt].x=0.f; ac0[nt].y=0.f; ac0[nt].z=0.f; ac0[nt].w=0.f;
                ac1[nt].x=0.f; ac1[nt].y=0.f; ac1[nt].z=0.f; ac1[nt].w=0.f;
            }
            #pragma unroll
            for (int nt = 0; nt < 2; nt++) {
                int gnt = q * 2 + nt;
                #pragma unroll
                for (int ks = 0; ks < 5; ks++) {
                    bf16x8 b = *(const bf16x8*)(w1s + ((gnt * 5 + ks) * 64 + lane) * 8);
                    ac0[nt] = mfma16(af0[ks], b, ac0[nt]);
                    ac1[nt] = mfma16(af1[ks], b, ac1[nt]);
                }
            }
            #pragma unroll
            for (int nt = 0; nt < 2; nt++) {
                float bb = b1r[q * 2 + nt];
                #pragma unroll
                for (int r = 0; r < 4; r++) {
                    float v0 = fmaxf(ac0[nt][r] + bb, 0.f);
                    float v1 = fmaxf(ac1[nt][r] + bb, 0.f);
                    hq[wv][(quad * 4 + r) * 36 + nt * 16 + l15]      = (bf16_t)v0;
                    hq[wv][(16 + quad * 4 + r) * 36 + nt * 16 + l15] = (bf16_t)v1;
                }
            }
            // same-wave write->read (compiler lgkmcnt)
            bf16x8 hf0 = *(const bf16x8*)(hq[wv] + l15 * 36 + quad * 8);
            bf16x8 hf1 = *(const bf16x8*)(hq[wv] + (16 + l15) * 36 + quad * 8);
            #pragma unroll
            for (int nt = 0; nt < 4; nt++) {
                bf16x8 w2 = *(const bf16x8*)(w2s + ((nt * 4 + q) * 64 + lane) * 8);
                oa0[nt] = mfma16(hf0, w2, oa0[nt]);
                oa1[nt] = mfma16(hf1, w2, oa1[nt]);
            }
        }

        // ---- prefetch next-pair A fragments BEFORE the store epilogue ----
        int base = p * 32;
        {
            const bf16_t* sp0 = hb + (size_t)si0n * 64 + quad * 8;
            const bf16_t* dp0 = hb + (size_t)di0n * 64 + quad * 8;
            const bf16_t* sp1 = hb + (size_t)si1n * 64 + quad * 8;
            const bf16_t* dp1 = hb + (size_t)di1n * 64 + quad * 8;
            af0[0] = *(const bf16x8*)sp0;  af0[1] = *(const bf16x8*)(sp0 + 32);
            af0[2] = *(const bf16x8*)dp0;  af0[3] = *(const bf16x8*)(dp0 + 32);
            af1[0] = *(const bf16x8*)sp1;  af1[1] = *(const bf16x8*)(sp1 + 32);
            af1[2] = *(const bf16x8*)dp1;  af1[3] = *(const bf16x8*)(dp1 + 32);
            if (quad == 0) {
                af0[4] = *(const bf16x8*)(efpb + (size_t)nr0 * 8);
                af1[4] = *(const bf16x8*)(efpb + (size_t)nr1 * 8);
            }
        }

        // ---- epilogue: plain bf16 stores of m (+b2), sorted edge order ----
        #pragma unroll
        for (int nt = 0; nt < 4; nt++) {
            int col = nt * 16 + l15;
            float bb = b2r[nt];
            #pragma unroll
            for (int r = 0; r < 4; r++) {
                int row0 = base + quad * 4 + r;
                int row1 = base + 16 + quad * 4 + r;
                mb[(size_t)row0 * 64 + col] = (bf16_t)(oa0[nt][r] + bb);
                mb[(size_t)row1 * 64 + col] = (bf16_t)(oa1[nt][r] + bb);
            }
        }

        if (pn >= NPAIR) break;
        p = pn;
    }
}

// ---------------------------------------------------------------------------
// agg kernel: wave-per-node CSR gather-sum over bf16 m rows, lane-per-col.
// Fully coalesced (128B per 64-lane load). Deterministic, zero atomics.
// Emits bf16 agg (GRU consumes bf16 directly).
// ---------------------------------------------------------------------------
__global__ __launch_bounds__(256) void agg_kernel(
    const bf16_t* __restrict__ mb, const int* __restrict__ deg,
    const int* __restrict__ cursor, bf16_t* __restrict__ aggb)
{
    const int node = blockIdx.x * 4 + (threadIdx.x >> 6);
    if (node >= NN) return;
    const int lane = threadIdx.x & 63;
    int dg  = deg[node];
    int end = cursor[node];
    int st  = end - dg;
    float s0 = 0.f, s1 = 0.f;
    int e = st;
    for (; e + 1 < end; e += 2) {
        s0 += (float)mb[(size_t)e * 64 + lane];
        s1 += (float)mb[(size_t)(e + 1) * 64 + lane];
    }
    if (e < end) s0 += (float)mb[(size_t)e * 64 + lane];
    aggb[(size_t)node * 64 + lane] = (bf16_t)(s0 + s1);
}

// ---------------------------------------------------------------------------
// GRU (MFMA): 64 nodes/block, 16/wave. agg input now bf16 (direct loads).
// LAST=0: emits fp32 h + bf16 hb. LAST=1: fused readout MLP.
// ---------------------------------------------------------------------------
template<int LAST>
__global__ __launch_bounds__(256) void gru_kernel(
    const bf16_t* __restrict__ aggb, const float* __restrict__ h_in,
    float* __restrict__ h_out, bf16_t* __restrict__ hb_out,
    const bf16_t* __restrict__ Wxt, const bf16_t* __restrict__ Wht,
    const float* __restrict__ bg,
    const bf16_t* __restrict__ Wr1f, const float* __restrict__ br1,
    const float* __restrict__ Wr2, const float* __restrict__ br2,
    float* __restrict__ out)
{
    __shared__ __attribute__((aligned(16))) float  shd[64 * 68];    // 17408 B
    __shared__ __attribute__((aligned(16))) bf16_t hb2[4][16 * 72]; //  9216 B
    const int tid = threadIdx.x;
    const int n0  = blockIdx.x * 64;

    for (int idx = tid; idx < 64 * 16; idx += 256) {
        int i = idx >> 4, c = (idx & 15) * 4;
        int n = n0 + i; if (n >= NN) n = NN - 1;
        *(float4*)&shd[i * 68 + c] = *(const float4*)(h_in + (size_t)n * 64 + c);
    }
    __syncthreads();

    const int lane = tid & 63;
    const int wv   = tid >> 6;
    const int l15  = lane & 15;
    const int quad = lane >> 4;
    const int rowA = wv * 16 + l15;
    int nA = n0 + rowA; if (nA >= NN) nA = NN - 1;

    bf16x8 ax[2], ah[2];
    ax[0] = *(const bf16x8*)(aggb + (size_t)nA * 64 + quad * 8);
    ax[1] = *(const bf16x8*)(aggb + (size_t)nA * 64 + quad * 8 + 32);
    {
        const float* hp = shd + rowA * 68 + quad * 8;
        ah[0] = cvt8(hp);
        ah[1] = cvt8(hp + 32);
    }

    floatx4 az[4], ar[4], axh[4], ahh[4];
    #pragma unroll
    for (int nt = 0; nt < 4; nt++) {
        az[nt].x=0.f; az[nt].y=0.f; az[nt].z=0.f; az[nt].w=0.f;
        ar[nt].x=0.f; ar[nt].y=0.f; ar[nt].z=0.f; ar[nt].w=0.f;
        axh[nt].x=0.f; axh[nt].y=0.f; axh[nt].z=0.f; axh[nt].w=0.f;
        ahh[nt].x=0.f; ahh[nt].y=0.f; ahh[nt].z=0.f; ahh[nt].w=0.f;
    }
    #pragma unroll
    for (int nt = 0; nt < 4; nt++) {
        const bf16_t* bx_z = Wxt + (nt * 16 + l15) * 64 + quad * 8;
        const bf16_t* bh_z = Wht + (nt * 16 + l15) * 64 + quad * 8;
        const bf16_t* bx_r = bx_z + 64 * 64;
        const bf16_t* bh_r = bh_z + 64 * 64;
        const bf16_t* bx_h = bx_z + 128 * 64;
        const bf16_t* bh_h = bh_z + 128 * 64;
        az[nt]  = mfma16(ax[0], *(const bf16x8*)bx_z,        az[nt]);
        az[nt]  = mfma16(ax[1], *(const bf16x8*)(bx_z + 32), az[nt]);
        az[nt]  = mfma16(ah[0], *(const bf16x8*)bh_z,        az[nt]);
        az[nt]  = mfma16(ah[1], *(const bf16x8*)(bh_z + 32), az[nt]);
        ar[nt]  = mfma16(ax[0], *(const bf16x8*)bx_r,        ar[nt]);
        ar[nt]  = mfma16(ax[1], *(const bf16x8*)(bx_r + 32), ar[nt]);
        ar[nt]  = mfma16(ah[0], *(const bf16x8*)bh_r,        ar[nt]);
        ar[nt]  = mfma16(ah[1], *(const bf16x8*)(bh_r + 32), ar[nt]);
        axh[nt] = mfma16(ax[0], *(const bf16x8*)bx_h,        axh[nt]);
        axh[nt] = mfma16(ax[1], *(const bf16x8*)(bx_h + 32), axh[nt]);
        ahh[nt] = mfma16(ah[0], *(const bf16x8*)bh_h,        ahh[nt]);
        ahh[nt] = mfma16(ah[1], *(const bf16x8*)(bh_h + 32), ahh[nt]);
    }

    #pragma unroll
    for (int nt = 0; nt < 4; nt++) {
        int j = nt * 16 + l15;
        float bz = bg[j], brr = bg[64 + j], bh = bg[128 + j];
        #pragma unroll
        for (int r = 0; r < 4; r++) {
            int lrow = wv * 16 + quad * 4 + r;
            int n = n0 + lrow;
            float z  = sigm_f(az[nt][r] + bz);
            float rr = sigm_f(ar[nt][r] + brr);
            float hc = tanh_f(axh[nt][r] + bh + rr * ahh[nt][r]);
            float hold = shd[lrow * 68 + j];
            float hnew = z * hold + (1.f - z) * hc;
            if (LAST) {
                hb2[wv][(quad * 4 + r) * 72 + j] = (bf16_t)hnew;
            } else if (n < NN) {
                h_out[(size_t)n * 64 + j]  = hnew;
                hb_out[(size_t)n * 64 + j] = (bf16_t)hnew;
            }
        }
    }

    if (LAST) {
        bf16x8 a0 = *(const bf16x8*)(hb2[wv] + l15 * 72 + quad * 8);
        bf16x8 a1 = *(const bf16x8*)(hb2[wv] + l15 * 72 + quad * 8 + 32);
        floatx4 accR[8];
        #pragma unroll
        for (int nt = 0; nt < 8; nt++) { accR[nt].x=0.f; accR[nt].y=0.f; accR[nt].z=0.f; accR[nt].w=0.f; }
        #pragma unroll
        for (int nt = 0; nt < 8; nt++) {
            bf16x8 b0 = *(const bf16x8*)(Wr1f + ((nt * 2 + 0) * 64 + lane) * 8);
            bf16x8 b1 = *(const bf16x8*)(Wr1f + ((nt * 2 + 1) * 64 + lane) * 8);
            accR[nt] = mfma16(a0, b0, accR[nt]);
            accR[nt] = mfma16(a1, b1, accR[nt]);
        }
        float br1r[8], wr2r[8];
        #pragma unroll
        for (int nt = 0; nt < 8; nt++) {
            br1r[nt] = br1[nt * 16 + l15];
            wr2r[nt] = Wr2[nt * 16 + l15];
        }
        float br2v = br2[0];
        #pragma unroll
        for (int r = 0; r < 4; r++) {
            float p = 0.f;
            #pragma unroll
            for (int nt = 0; nt < 8; nt++)
                p += fmaxf(accR[nt][r] + br1r[nt], 0.f) * wr2r[nt];
            p += __shfl_xor(p, 1, 64);
            p += __shfl_xor(p, 2, 64);
            p += __shfl_xor(p, 4, 64);
            p += __shfl_xor(p, 8, 64);
            if (l15 == 0) {
                int n = n0 + wv * 16 + quad * 4 + r;
                if (n < NN) out[n] = p + br2v;
            }
        }
    }
}

// ---------------------------------------------------------------------------
extern "C" void kernel_launch(void* const* d_in, const int* in_sizes, int n_in,
                              void* d_out, int out_size, void* d_ws, size_t ws_size,
                              hipStream_t stream)
{
    const float* nf  = (const float*)d_in[0];
    const float* ef  = (const float*)d_in[1];
    const int* esrc  = (const int*)d_in[2];
    const int* edst  = (const int*)d_in[3];
    const float* Wm1 = (const float*)d_in[4];
    const float* bm1 = (const float*)d_in[5];
    const float* Wm2 = (const float*)d_in[6];
    const float* bm2 = (const float*)d_in[7];
    const float* Wx  = (const float*)d_in[8];
    const float* Wh  = (const float*)d_in[9];
    const float* bg  = (const float*)d_in[10];
    const float* Wr1 = (const float*)d_in[11];
    const float* br1 = (const float*)d_in[12];
    const float* Wr2 = (const float*)d_in[13];
    const float* br2 = (const float*)d_in[14];

    char* ws = (char*)d_ws;
    float*  hbuf   = (float*)(ws);                   // 12,800,000
    bf16_t* hb     = (bf16_t*)(ws + 12800000);       // 6,400,000
    bf16_t* W1f    = (bf16_t*)(ws + 19200000);       // 40,960
    bf16_t* W2f    = (bf16_t*)(ws + 19240960);       // 16,384
    bf16_t* Wxt    = (bf16_t*)(ws + 19257344);       // 24,576
    bf16_t* Wht    = (bf16_t*)(ws + 19281920);       // 24,576
    bf16_t* Wr1f   = (bf16_t*)(ws + 19306496);       // 16,384
    int*    srcs   = (int*)(ws + 19322880);          // 1,600,000
    int*    dsts   = (int*)(ws + 20922880);          // 1,600,000
    bf16_t* efpb   = (bf16_t*)(ws + 22522880);       // 6,400,000
    int*    deg    = (int*)(ws + 28922880);          // 200,704
    int*    cursor = (int*)(ws + 29123584);          // 200,704
    int*    chunkS = (int*)(ws + 29324288);          // 1,024
    int*    chunkO = (int*)(ws + 29325312);          // 1,024
    bf16_t* aggb   = (bf16_t*)(ws + 29326336);       // 6,400,000
    bf16_t* mb     = (bf16_t*)(ws + 35726336);       // 51,200,000

    prep_kernel<<<3365, 256, 0, stream>>>(nf, Wm1, Wm2, Wx, Wh, Wr1,
                                          hb, W1f, W2f, Wxt, Wht, Wr1f);

    // CSR build (same work every call)
    hipMemsetAsync(deg, 0, (size_t)NPAD * 4, stream);
    hist_kernel<<<(NE + 255) / 256, 256, 0, stream>>>(edst, deg);
    scanA_kernel<<<NCH, 256, 0, stream>>>(deg, chunkS);
    scanB_kernel<<<1, 256, 0, stream>>>(chunkS, chunkO);
    scanC_kernel<<<NCH, 256, 0, stream>>>(deg, chunkO, cursor);
    scatter_kernel<<<(NE + 255) / 256, 256, 0, stream>>>(esrc, edst, ef, cursor,
                                                         srcs, dsts, efpb);

    // step 0
    edge_kernel<<<1024, 256, 0, stream>>>(hb, efpb, srcs, dsts,
                                          W1f, W2f, bm1, bm2, mb);
    agg_kernel<<<(NN + 3) / 4, 256, 0, stream>>>(mb, deg, cursor, aggb);
    gru_kernel<0><<<(NN + 63) / 64, 256, 0, stream>>>(
        aggb, nf, hbuf, hb, Wxt, Wht, bg, Wr1f, br1, Wr2, br2, (float*)d_out);
    // step 1
    edge_kernel<<<1024, 256, 0, stream>>>(hb, efpb, srcs, dsts,
                                          W1f, W2f, bm1, bm2, mb);
    agg_kernel<<<(NN + 3) / 4, 256, 0, stream>>>(mb, deg, cursor, aggb);
    gru_kernel<1><<<(NN + 63) / 64, 256, 0, stream>>>(
        aggb, hbuf, nullptr, nullptr, Wxt, Wht, bg, Wr1f, br1, Wr2, br2,
        (float*)d_out);
}